// Round 1
// baseline (1670.032 us; speedup 1.0000x reference)
//
#include <hip/hip_runtime.h>
#include <stdint.h>

// Problem constants
#define NPTS 400000
#define DIM  128
#define KNB  27
#define NSEG 8

typedef _Float16 f16x8 __attribute__((ext_vector_type(8)));
typedef float floatx16 __attribute__((ext_vector_type(16)));

// Workspace layout (bytes). Total ~309 MB.
#define OFF_FEATSH 0UL                    // N*128 f16 = 102,400,000
#define OFF_OUT1   102400000UL            // N*128 f16
#define OFF_OUT2   204800000UL            // N*128 f16
#define OFF_PW1    307200000UL            // 27*128*128 f16 = 884,736
#define OFF_PW2    308084736UL
#define OFF_PW3    308969472UL            // 128*128 f16 = 32,768
#define OFF_SEG    309002240UL            // 8*128 f32 = 4096
#define OFF_CNT    309006336UL            // 8 f32 = 32

__device__ __forceinline__ void load_lds16(const void* g, void* l) {
  __builtin_amdgcn_global_load_lds(
      (const __attribute__((address_space(1))) void*)g,
      (__attribute__((address_space(3))) void*)l, 16, 0, 0);
}

// ---------------- feats fp32 -> f16 ----------------
__global__ __launch_bounds__(256) void cvt_feats(const float* __restrict__ f,
                                                 _Float16* __restrict__ fh) {
  size_t g = (size_t)blockIdx.x * 256 + threadIdx.x;   // 6,400,000 threads, 8 elems each
  const float4* src = (const float4*)f;
  float4 v0 = src[g * 2], v1 = src[g * 2 + 1];
  f16x8 o;
  o[0] = (_Float16)v0.x; o[1] = (_Float16)v0.y; o[2] = (_Float16)v0.z; o[3] = (_Float16)v0.w;
  o[4] = (_Float16)v1.x; o[5] = (_Float16)v1.y; o[6] = (_Float16)v1.z; o[7] = (_Float16)v1.w;
  ((f16x8*)fh)[g] = o;
}

// ---------------- pack W1/W2/W3 into B-fragment order ----------------
// B frag for mfma_f32_32x32x16_f16: lane holds 8 f16: B[kk][c], c = ct*32+(lane&31),
// kk = ko*16 + (lane>>5)*8 + j. Packed flat: [k][ko][ct][lane][8].
__global__ __launch_bounds__(256) void pack_w(const float* __restrict__ W1,
                                              const float* __restrict__ W2,
                                              const float* __restrict__ W3,
                                              _Float16* __restrict__ pW1,
                                              _Float16* __restrict__ pW2,
                                              _Float16* __restrict__ pW3) {
  int gid = blockIdx.x * 256 + threadIdx.x;            // 112,640 total
  const float* W; _Float16* dst; int k, rem;
  if (gid < 110592) {
    int mat = gid / 55296, r = gid % 55296;
    W = mat ? W2 : W1; dst = (mat ? pW2 : pW1) + (size_t)r * 8;
    k = r >> 11; rem = r & 2047;
  } else {
    int r = gid - 110592;                              // 0..2047
    W = W3; dst = pW3 + (size_t)r * 8; k = 0; rem = r;
  }
  int ko = rem >> 8, ct = (rem >> 6) & 3, lane = rem & 63;
  int h = lane >> 5, c = ct * 32 + (lane & 31);
  f16x8 o;
#pragma unroll
  for (int j = 0; j < 8; ++j) {
    int kk = ko * 16 + h * 8 + j;
    o[j] = (_Float16)W[(size_t)(k * 128 + kk) * 128 + c];
  }
  *(f16x8*)dst = o;
}

// ---------------- conv kernel: out1/out2 = relu(sum_k mask*gather @ Wk + b) ----------------
// Block = 256 thr (4 waves) = 128 rows. wave -> conv = w>>1, rowgroup g = w&1 (64 rows).
// Each wave: 2 row-tiles of 32 x full 128 cols; B frags from LDS (reused across the 2
// row-tiles -> 0.5KB LDS read per MFMA, compute-bound); A gathered per-lane from global.
__global__ __launch_bounds__(256, 2) void conv_kernel(
    const _Float16* __restrict__ featsh, const int* __restrict__ nidx,
    const int* __restrict__ nmask, const int* __restrict__ segids,
    const _Float16* __restrict__ pW1, const _Float16* __restrict__ pW2,
    const float* __restrict__ b1, const float* __restrict__ b2,
    _Float16* __restrict__ out1, _Float16* __restrict__ out2,
    float* __restrict__ seg_sums, float* __restrict__ cnts_f) {
  __shared__ __align__(16) char lds_raw[65536];        // W1|W2 staging, then out1|out2 transpose
  int tid = threadIdx.x, w = tid >> 6, lane = tid & 63;
  int conv = w >> 1, g = w & 1, h = lane >> 5;
  int n0 = blockIdx.x * 128;
  int row0 = n0 + g * 64 + (lane & 31);
  int row1 = row0 + 32;

  floatx16 acc0[4], acc1[4];
#pragma unroll
  for (int ct = 0; ct < 4; ++ct)
#pragma unroll
    for (int r = 0; r < 16; ++r) { acc0[ct][r] = 0.f; acc1[ct][r] = 0.f; }

  const char* srcW = (const char*)(w < 2 ? pW1 : pW2) + (w & 1) * 16384;

  for (int k = 0; k < KNB; ++k) {
    __syncthreads();
    // stage this k's packed W1+W2 (64KB): each wave 16KB via global_load_lds x16
    const char* sk = srcW + (size_t)k * 32768;
    char* ldsb = lds_raw + w * 16384;
#pragma unroll
    for (int it = 0; it < 16; ++it)
      load_lds16(sk + it * 1024 + lane * 16, ldsb + it * 1024);
    int i0 = nidx[row0 * KNB + k]; int m0 = nmask[row0 * KNB + k];
    int i1 = nidx[row1 * KNB + k]; int m1 = nmask[row1 * KNB + k];
    __syncthreads();
    const _Float16* ldsW = (const _Float16*)(lds_raw + conv * 32768);
    const _Float16* ar0 = featsh + (size_t)i0 * 128 + h * 8;
    const _Float16* ar1 = featsh + (size_t)i1 * 128 + h * 8;
#pragma unroll
    for (int ko = 0; ko < 8; ++ko) {
      uint4 a0u = {0, 0, 0, 0}, a1u = {0, 0, 0, 0};
      if (m0) a0u = *(const uint4*)(ar0 + ko * 16);
      if (m1) a1u = *(const uint4*)(ar1 + ko * 16);
      f16x8 a0 = __builtin_bit_cast(f16x8, a0u);
      f16x8 a1 = __builtin_bit_cast(f16x8, a1u);
#pragma unroll
      for (int ct = 0; ct < 4; ++ct) {
        f16x8 b = *(const f16x8*)(ldsW + ((ko * 4 + ct) * 64 + lane) * 8);
        acc0[ct] = __builtin_amdgcn_mfma_f32_32x32x16_f16(a0, b, acc0[ct], 0, 0, 0);
        acc1[ct] = __builtin_amdgcn_mfma_f32_32x32x16_f16(a1, b, acc1[ct], 0, 0, 0);
      }
    }
  }

  // epilogue: bias + relu
  const float* bb = conv ? b2 : b1;
  float bias[4];
#pragma unroll
  for (int ct = 0; ct < 4; ++ct) bias[ct] = bb[ct * 32 + (lane & 31)];
#pragma unroll
  for (int ct = 0; ct < 4; ++ct)
#pragma unroll
    for (int r = 0; r < 16; ++r) {
      acc0[ct][r] = fmaxf(acc0[ct][r] + bias[ct], 0.f);
      acc1[ct][r] = fmaxf(acc1[ct][r] + bias[ct], 0.f);
    }

  int seg0 = segids[n0];
  bool uniform = (seg0 == segids[n0 + 127]);   // segment_ids are sorted

  // segment column sums of out2 (uniform fast path: per-wave shuffle reduce + atomics)
  if (conv == 1 && uniform) {
#pragma unroll
    for (int ct = 0; ct < 4; ++ct) {
      float s = 0.f;
#pragma unroll
      for (int r = 0; r < 16; ++r) s += acc0[ct][r] + acc1[ct][r];
      s += __shfl_xor(s, 32);
      if (lane < 32) atomicAdd(&seg_sums[seg0 * 128 + ct * 32 + lane], s);
    }
  }
  if (tid == 0 && uniform) atomicAdd(&cnts_f[seg0], 128.0f);

  __syncthreads();                             // all waves done reading staged W
  // transpose C-layout accs -> row-major f16 in LDS
  _Float16* lds_out = (_Float16*)lds_raw;      // [2][128][128]
#pragma unroll
  for (int ct = 0; ct < 4; ++ct) {
    int col = ct * 32 + (lane & 31);
#pragma unroll
    for (int r = 0; r < 16; ++r) {
      int lr = g * 64 + (r & 3) + 8 * (r >> 2) + 4 * h;   // C/D row mapping (m74/m101)
      lds_out[conv * 16384 + lr * 128 + col] = (_Float16)acc0[ct][r];
      lds_out[conv * 16384 + (lr + 32) * 128 + col] = (_Float16)acc1[ct][r];
    }
  }
  __syncthreads();

  if (!uniform && tid < 128) {                 // rare boundary blocks: per-row atomics
    int s = segids[n0 + tid];
    atomicAdd(&cnts_f[s], 1.0f);
    for (int c = 0; c < 128; ++c)
      atomicAdd(&seg_sums[s * 128 + c], (float)lds_out[16384 + tid * 128 + c]);
  }

  // coalesced row-major stores of out1/out2 (64KB total)
#pragma unroll
  for (int it = 0; it < 16; ++it) {
    int chunk = it * 256 + tid;                // 0..4095, 16B each
    int cv = chunk >> 11;
    int off16 = chunk & 2047;
    uint4 v = *(const uint4*)(lds_raw + cv * 32768 + off16 * 16);
    *(uint4*)((cv ? out2 : out1) + (size_t)n0 * 128 + off16 * 8) = v;
  }
}

// ---------------- final kernel: enc/mid + mid@W3 + relu(feats - relu(.)) ----------------
__global__ __launch_bounds__(256, 2) void final_kernel(
    const float* __restrict__ feats, const _Float16* __restrict__ out1,
    const _Float16* __restrict__ out2, const int* __restrict__ segids,
    const float* __restrict__ seg_sums, const float* __restrict__ cnts_f,
    const char* __restrict__ pW3, const float* __restrict__ b3,
    float* __restrict__ dout) {
  __shared__ __align__(16) char ldsw3[32768];
  __shared__ float smean[NSEG * 128];
  int tid = threadIdx.x, w = tid >> 6, lane = tid & 63, h = lane >> 5;
  int n0 = blockIdx.x * 128;
#pragma unroll
  for (int it = 0; it < 8; ++it)
    load_lds16(pW3 + w * 8192 + it * 1024 + lane * 16, ldsw3 + w * 8192 + it * 1024);
  for (int i = tid; i < NSEG * 128; i += 256)
    smean[i] = seg_sums[i] / fmaxf(cnts_f[i >> 7], 1.0f);
  __syncthreads();

  int row = n0 + w * 32 + (lane & 31);
  int seg = segids[row];
  const char* p1 = (const char*)(out1 + (size_t)row * 128 + h * 8);
  const char* p2 = (const char*)(out2 + (size_t)row * 128 + h * 8);
  f16x8 o1[8], o2[8];
  float s1 = 0.f;
#pragma unroll
  for (int ko = 0; ko < 8; ++ko) {
    o1[ko] = *(const f16x8*)(p1 + ko * 32);
    o2[ko] = *(const f16x8*)(p2 + ko * 32);
#pragma unroll
    for (int j = 0; j < 8; ++j) s1 += (float)o1[ko][j];
  }
  s1 += __shfl_xor(s1, 32);
  float rm = s1 * (1.0f / 128.0f);             // row mean of out1 (out1 >= 0)

  f16x8 a[8];
#pragma unroll
  for (int ko = 0; ko < 8; ++ko) {
    int colb = ko * 16 + h * 8;
#pragma unroll
    for (int j = 0; j < 8; ++j) {
      float m2 = smean[seg * 128 + colb + j];
      float e = sqrtf(fmaf(rm, m2, 1e-12f));
      a[ko][j] = (_Float16)(e + (float)o1[ko][j] + (float)o2[ko][j]);
    }
  }
  floatx16 acc[4];
#pragma unroll
  for (int ct = 0; ct < 4; ++ct)
#pragma unroll
    for (int r = 0; r < 16; ++r) acc[ct][r] = 0.f;
#pragma unroll
  for (int ko = 0; ko < 8; ++ko)
#pragma unroll
    for (int ct = 0; ct < 4; ++ct) {
      f16x8 b = *(const f16x8*)(ldsw3 + ((ko * 4 + ct) * 64 + lane) * 16);
      acc[ct] = __builtin_amdgcn_mfma_f32_32x32x16_f16(a[ko], b, acc[ct], 0, 0, 0);
    }
#pragma unroll
  for (int ct = 0; ct < 4; ++ct) {
    int col = ct * 32 + (lane & 31);
    float bc = b3[col];
#pragma unroll
    for (int r = 0; r < 16; ++r) {
      int gr = n0 + w * 32 + (r & 3) + 8 * (r >> 2) + 4 * h;
      float v = fmaxf(acc[ct][r] + bc, 0.f);
      float f = feats[(size_t)gr * 128 + col];
      dout[(size_t)gr * 128 + col] = fmaxf(f - v, 0.f);
    }
  }
}

extern "C" void kernel_launch(void* const* d_in, const int* in_sizes, int n_in,
                              void* d_out, int out_size, void* d_ws, size_t ws_size,
                              hipStream_t stream) {
  (void)in_sizes; (void)n_in; (void)out_size; (void)ws_size;
  const float* feats = (const float*)d_in[0];
  const int* nidx   = (const int*)d_in[1];
  const int* nmask  = (const int*)d_in[2];   // bool mask; assumed int32 per harness convention
  const int* segids = (const int*)d_in[3];
  const float* W1 = (const float*)d_in[5];
  const float* b1 = (const float*)d_in[6];
  const float* W2 = (const float*)d_in[7];
  const float* b2 = (const float*)d_in[8];
  const float* W3 = (const float*)d_in[9];
  const float* b3 = (const float*)d_in[10];
  float* dout = (float*)d_out;
  char* ws = (char*)d_ws;

  _Float16* featsh = (_Float16*)(ws + OFF_FEATSH);
  _Float16* out1h  = (_Float16*)(ws + OFF_OUT1);
  _Float16* out2h  = (_Float16*)(ws + OFF_OUT2);
  _Float16* pW1    = (_Float16*)(ws + OFF_PW1);
  _Float16* pW2    = (_Float16*)(ws + OFF_PW2);
  _Float16* pW3    = (_Float16*)(ws + OFF_PW3);
  float* seg_sums  = (float*)(ws + OFF_SEG);
  float* cnts_f    = (float*)(ws + OFF_CNT);

  hipMemsetAsync(ws + OFF_SEG, 0, 4096 + 32, stream);
  cvt_feats<<<25000, 256, 0, stream>>>(feats, featsh);
  pack_w<<<440, 256, 0, stream>>>(W1, W2, W3, pW1, pW2, pW3);
  conv_kernel<<<3125, 256, 0, stream>>>(featsh, nidx, nmask, segids, pW1, pW2,
                                        b1, b2, out1h, out2h, seg_sums, cnts_f);
  final_kernel<<<3125, 256, 0, stream>>>(feats, out1h, out2h, segids, seg_sums,
                                         cnts_f, (const char*)pW3, b3, dout);
}